// Round 1
// baseline (561.879 us; speedup 1.0000x reference)
//
#include <hip/hip_runtime.h>
#include <hip/hip_bf16.h>
#include <math.h>

#define N_ITEMS 2900000
#define BDIM 4096
#define DDIM 768

typedef float f32x4 __attribute__((ext_vector_type(4)));
typedef __bf16 bf16x8 __attribute__((ext_vector_type(8)));

__device__ inline unsigned short f2bf(float f) {
    unsigned int u = __float_as_uint(f);
    unsigned int lsb = (u >> 16) & 1u;
    u += 0x7fffu + lsb;
    return (unsigned short)(u >> 16);
}

// ---------------- copy 8 N-length state arrays to output (pass-through) ----
__global__ void copy_kernel(const float* s0, const float* s1, const float* s2, const float* s3,
                            const float* s4, const float* s5, const float* s6, const float* s7,
                            float* dst) {
    const int n4 = N_ITEMS / 4;
    int k = blockIdx.y;
    const float* s;
    switch (k) {
        case 0: s = s0; break; case 1: s = s1; break;
        case 2: s = s2; break; case 3: s = s3; break;
        case 4: s = s4; break; case 5: s = s5; break;
        case 6: s = s6; break; default: s = s7; break;
    }
    float* d = dst + (size_t)k * N_ITEMS;
    for (int i = blockIdx.x * blockDim.x + threadIdx.x; i < n4; i += gridDim.x * blockDim.x) {
        float4 v = ((const float4*)s)[i];
        float* dd = d + (size_t)i * 4;   // dst is 4B-aligned only (offset 8193 floats)
        dd[0] = v.x; dd[1] = v.y; dd[2] = v.z; dd[3] = v.w;
    }
}

// ---------------- fp32 -> bf16 conversion of img / txt ---------------------
__global__ void convert_kernel(const float* __restrict__ img, const float* __restrict__ txt,
                               unsigned short* __restrict__ Xbf, unsigned short* __restrict__ Ybf) {
    const int per = (BDIM * DDIM) / 4;  // 786432 float4 units per array
    for (int u = blockIdx.x * blockDim.x + threadIdx.x; u < 2 * per; u += gridDim.x * blockDim.x) {
        const float4* src = (u < per) ? (const float4*)img : (const float4*)txt;
        unsigned short* dst = (u < per) ? Xbf : Ybf;
        int i = (u < per) ? u : u - per;
        float4 v = src[i];
        ushort4 o;
        o.x = f2bf(v.x); o.y = f2bf(v.y); o.z = f2bf(v.z); o.w = f2bf(v.w);
        ((ushort4*)dst)[i] = o;
    }
}

// ---------------- fp32 diagonal dot + tau gathers --------------------------
__global__ void diag_tau_kernel(const float* __restrict__ img, const float* __restrict__ txt,
                                const int* __restrict__ image_ids, const int* __restrict__ text_ids,
                                const float* __restrict__ tau_I, const float* __restrict__ tau_T,
                                float* __restrict__ diag, float* __restrict__ tau_row,
                                float* __restrict__ out /* d_out base */) {
    int w = (blockIdx.x * blockDim.x + threadIdx.x) >> 6;
    int lane = threadIdx.x & 63;
    if (w >= BDIM) return;
    const float* a = img + (size_t)w * DDIM;
    const float* b = txt + (size_t)w * DDIM;
    float s = 0.f;
    for (int d = lane; d < DDIM; d += 64) s += a[d] * b[d];
    #pragma unroll
    for (int d = 32; d >= 1; d >>= 1) s += __shfl_xor(s, d);
    if (lane == 0) diag[w] = s;
    if (lane == 1) {
        int id = image_ids[w];
        float t = tau_I[id];
        tau_row[w] = t;
        out[1 + w] = t;           // output 1: tau_image
    }
    if (lane == 2) {
        int id = text_ids[w];
        float t = tau_T[id];
        tau_row[BDIM + w] = t;
        out[1 + BDIM + w] = t;    // output 2: tau_text
    }
}

// ---------------- fused bf16 MFMA GEMM + per-chunk online softmax ----------
// grid: (32 colblocks, 32 rowblocks, 2 passes), 256 threads (4 waves, 2x2)
// pass 0: rows = image i over sim;  pass 1: rows = text j over sim^T
__global__ __launch_bounds__(256) void gemm_kernel(
        const unsigned short* __restrict__ Xbf, const unsigned short* __restrict__ Ybf,
        const float* __restrict__ diag, const float* __restrict__ tau_row,
        float* __restrict__ partials /* [2][4096][64][3] */) {
    __shared__ unsigned short As[128 * 40];   // 32 k + 8 pad per row
    __shared__ unsigned short Bs[128 * 40];
    const int tid = threadIdx.x;
    const int lane = tid & 63;
    const int wave = tid >> 6;
    const int wr = wave >> 1, wc = wave & 1;
    const int cb = blockIdx.x, rb = blockIdx.y, p = blockIdx.z;
    const unsigned short* Xp = p ? Ybf : Xbf;
    const unsigned short* Yp = p ? Xbf : Ybf;

    f32x4 acc[4][4];
    #pragma unroll
    for (int m = 0; m < 4; m++)
        #pragma unroll
        for (int n = 0; n < 4; n++)
            #pragma unroll
            for (int q = 0; q < 4; q++) acc[m][n][q] = 0.f;

    const int g = lane >> 4, r16 = lane & 15;
    const int ua_r0 = tid >> 2, ua_c = tid & 3;   // 16B unit: rows 0..63
    const int ua_r1 = ua_r0 + 64;                 // rows 64..127

    for (int kk = 0; kk < 24; ++kk) {
        __syncthreads();
        {
            const int kbase = kk * 32 + ua_c * 8;
            *(uint4*)&As[ua_r0 * 40 + ua_c * 8] = *(const uint4*)&Xp[(size_t)(rb * 128 + ua_r0) * DDIM + kbase];
            *(uint4*)&As[ua_r1 * 40 + ua_c * 8] = *(const uint4*)&Xp[(size_t)(rb * 128 + ua_r1) * DDIM + kbase];
            *(uint4*)&Bs[ua_r0 * 40 + ua_c * 8] = *(const uint4*)&Yp[(size_t)(cb * 128 + ua_r0) * DDIM + kbase];
            *(uint4*)&Bs[ua_r1 * 40 + ua_c * 8] = *(const uint4*)&Yp[(size_t)(cb * 128 + ua_r1) * DDIM + kbase];
        }
        __syncthreads();
        bf16x8 af[4], bfr[4];
        #pragma unroll
        for (int m = 0; m < 4; m++) af[m]  = *(const bf16x8*)&As[(wr * 64 + m * 16 + r16) * 40 + g * 8];
        #pragma unroll
        for (int n = 0; n < 4; n++) bfr[n] = *(const bf16x8*)&Bs[(wc * 64 + n * 16 + r16) * 40 + g * 8];
        #pragma unroll
        for (int m = 0; m < 4; m++)
            #pragma unroll
            for (int n = 0; n < 4; n++)
                acc[m][n] = __builtin_amdgcn_mfma_f32_16x16x32_bf16(af[m], bfr[n], acc[m][n], 0, 0, 0);
    }

    // epilogue: per-row online (m, E=sum e, F=sum e*x) over this wave's 64 cols
    const float* taup = tau_row + p * BDIM;
    const int R0 = rb * 128 + wr * 64;
    const int C0 = cb * 128 + wc * 64;
    #pragma unroll
    for (int m = 0; m < 4; m++) {
        #pragma unroll
        for (int q = 0; q < 4; q++) {
            const int rowg = R0 + m * 16 + g * 4 + q;
            const float dgv = diag[rowg];
            const float itau = 1.0f / taup[rowg];
            float mloc = -3.0e38f, E = 0.f, F = 0.f;
            #pragma unroll
            for (int n = 0; n < 4; n++) {
                const int colg = C0 + n * 16 + r16;
                if (colg == rowg) continue;          // mask_neg: skip diagonal
                float x = (acc[m][n][q] - dgv) * itau;
                if (x > mloc) {
                    float sc = __expf(mloc - x);
                    E *= sc; F *= sc; mloc = x;
                }
                float e = __expf(x - mloc);
                E += e; F += e * x;
            }
            // merge the 16 lanes (same l>>4) holding this row
            #pragma unroll
            for (int d = 1; d < 16; d <<= 1) {
                float mo = __shfl_xor(mloc, d);
                float Eo = __shfl_xor(E, d);
                float Fo = __shfl_xor(F, d);
                float mn = fmaxf(mloc, mo);
                float s1 = __expf(mloc - mn), s2 = __expf(mo - mn);
                E = E * s1 + Eo * s2;
                F = F * s1 + Fo * s2;
                mloc = mn;
            }
            if (r16 == 0) {
                const int chunk = cb * 2 + wc;       // 64-col chunk id, 0..63
                float* pp = partials + (((size_t)p * BDIM + rowg) * 64 + chunk) * 3;
                pp[0] = mloc; pp[1] = E; pp[2] = F;
            }
        }
    }
}

// ---------------- merge 64 chunk-partials per row + scalar tail math -------
__global__ void combine_kernel(const float* __restrict__ partials,
        const int* __restrict__ image_ids, const int* __restrict__ text_ids,
        const float* __restrict__ b_I, const float* __restrict__ b_T,
        const float* __restrict__ s_I, const float* __restrict__ s_T,
        const float* __restrict__ u_I, const float* __restrict__ u_T,
        const float* __restrict__ tau_row, const int* __restrict__ epoch_ptr,
        float* __restrict__ res /* [2][4096][5] = newb,s,u,tau,loss */) {
    int gw = (blockIdx.x * blockDim.x + threadIdx.x) >> 6;
    int lane = threadIdx.x & 63;
    if (gw >= 2 * BDIM) return;
    int p = gw >> 12, row = gw & (BDIM - 1);
    const float* pp = partials + (((size_t)p * BDIM + row) * 64 + lane) * 3;
    float m = pp[0], E = pp[1], F = pp[2];
    #pragma unroll
    for (int d = 1; d < 64; d <<= 1) {
        float mo = __shfl_xor(m, d), Eo = __shfl_xor(E, d), Fo = __shfl_xor(F, d);
        float mn = fmaxf(m, mo);
        float s1 = expf(m - mn), s2 = expf(mo - mn);
        E = E * s1 + Eo * s2;
        F = F * s1 + Fo * s2;
        m = mn;
    }
    if (lane == 0) {
        int id  = p ? text_ids[row] : image_ids[row];
        float ob = p ? b_T[id] : b_I[id];
        float so = p ? s_T[id] : s_I[id];
        float uo = p ? u_T[id] : u_I[id];
        float tv = tau_row[p * BDIM + row];
        float m0 = fmaxf(ob, 0.0f);        // reference max includes idt[i,i]=0 and old_b
        if (m0 > m) { float sc = expf(m - m0); E *= sc; F *= sc; m = m0; }
        float gsum = E;
        float sI = (*epoch_ptr == 0) ? gsum
                 : 0.2f * so * expf(ob - m) + 0.8f * gsum;
        float sc_ = fmaxf(sI, 1e-14f);
        float ratio = F / sc_;
        float lossv = tv * ratio;                                  // sum(w*diffs)
        float twi = logf(sc_ * (1.0f / 4095.0f)) + m + 8.0f - ratio;
        float uc = fminf(fmaxf(twi, -5.0f), 5.0f);
        float ub = 0.5f * uo + 0.5f * uc;
        float tb = fminf(fmaxf(tv - 0.03f * ub, 0.005f), 0.05f);
        float* r_ = res + ((size_t)p * BDIM + row) * 5;
        r_[0] = m; r_[1] = sI; r_[2] = ub; r_[3] = tb; r_[4] = lossv;
    }
}

// ---------------- scatter with numpy last-occurrence-wins semantics --------
__global__ void scatter_kernel(const float* __restrict__ res,
        const int* __restrict__ image_ids, const int* __restrict__ text_ids,
        float* __restrict__ out) {
    int t = blockIdx.x * blockDim.x + threadIdx.x;
    if (t >= 2 * BDIM) return;
    int p = t >> 12, b = t & (BDIM - 1);
    const int* ids = p ? text_ids : image_ids;
    int myid = ids[b];
    for (int b2 = b + 1; b2 < BDIM; ++b2)
        if (ids[b2] == myid) return;       // a later duplicate wins
    const float* r_ = res + ((size_t)p * BDIM + b) * 5;
    const size_t base = 1 + 2 * BDIM;      // 8193
    out[base + (size_t)(2 + p) * N_ITEMS + myid] = r_[0];  // b_I / b_T
    out[base + (size_t)(0 + p) * N_ITEMS + myid] = r_[1];  // s_I / s_T
    out[base + (size_t)(4 + p) * N_ITEMS + myid] = r_[2];  // u_I / u_T
    out[base + (size_t)(6 + p) * N_ITEMS + myid] = r_[3];  // tau_I / tau_T
}

// ---------------- deterministic loss reduction -----------------------------
__global__ void loss_kernel(const float* __restrict__ res, float* __restrict__ out) {
    __shared__ float wsum[16];
    int t = threadIdx.x;
    float s = 0.f;
    for (int i = t; i < 2 * BDIM; i += 1024) s += res[(size_t)i * 5 + 4];
    #pragma unroll
    for (int d = 32; d >= 1; d >>= 1) s += __shfl_xor(s, d);
    if ((t & 63) == 0) wsum[t >> 6] = s;
    __syncthreads();
    if (t == 0) {
        float tot = 0.f;
        for (int i = 0; i < 16; i++) tot += wsum[i];
        out[0] = tot * (1.0f / (float)BDIM);  // mean(img)+mean(txt) = sum(all)/B
    }
}

extern "C" void kernel_launch(void* const* d_in, const int* in_sizes, int n_in,
                              void* d_out, int out_size, void* d_ws, size_t ws_size,
                              hipStream_t stream) {
    const float* img       = (const float*)d_in[0];
    const float* txt       = (const float*)d_in[1];
    const int*   image_ids = (const int*)d_in[2];
    const int*   text_ids  = (const int*)d_in[3];
    const int*   epoch     = (const int*)d_in[4];
    const float* s_I   = (const float*)d_in[6];
    const float* s_T   = (const float*)d_in[7];
    const float* b_I   = (const float*)d_in[8];
    const float* b_T   = (const float*)d_in[9];
    const float* u_I   = (const float*)d_in[10];
    const float* u_T   = (const float*)d_in[11];
    const float* tau_I = (const float*)d_in[12];
    const float* tau_T = (const float*)d_in[13];
    float* out = (float*)d_out;

    char* ws = (char*)d_ws;
    unsigned short* Xbf = (unsigned short*)ws;                    // 6,291,456 B
    unsigned short* Ybf = (unsigned short*)(ws + 6291456);        // 6,291,456 B
    float* diag     = (float*)(ws + 12582912);                    // 16 KB
    float* tau_row  = (float*)(ws + 12599296);                    // 32 KB
    float* partials = (float*)(ws + 12632064);                    // 6,291,456 B
    float* res      = (float*)(ws + 18923520);                    // 160 KB

    copy_kernel<<<dim3(512, 8), 256, 0, stream>>>(s_I, s_T, b_I, b_T, u_I, u_T, tau_I, tau_T,
                                                  out + 1 + 2 * BDIM);
    convert_kernel<<<1536, 256, 0, stream>>>(img, txt, Xbf, Ybf);
    diag_tau_kernel<<<1024, 256, 0, stream>>>(img, txt, image_ids, text_ids, tau_I, tau_T,
                                              diag, tau_row, out);
    gemm_kernel<<<dim3(32, 32, 2), 256, 0, stream>>>(Xbf, Ybf, diag, tau_row, partials);
    combine_kernel<<<2048, 256, 0, stream>>>(partials, image_ids, text_ids,
                                             b_I, b_T, s_I, s_T, u_I, u_T,
                                             tau_row, epoch, res);
    scatter_kernel<<<32, 256, 0, stream>>>(res, image_ids, text_ids, out);
    loss_kernel<<<1, 1024, 0, stream>>>(res, out);
}

// Round 2
// 482.751 us; speedup vs baseline: 1.1639x; 1.1639x over previous
//
#include <hip/hip_runtime.h>
#include <hip/hip_bf16.h>
#include <math.h>

#define N_ITEMS 2900000
#define BDIM 4096
#define DDIM 768

typedef float f32x4 __attribute__((ext_vector_type(4)));
typedef __bf16 bf16x8 __attribute__((ext_vector_type(8)));

__device__ inline unsigned short f2bf(float f) {
    unsigned int u = __float_as_uint(f);
    unsigned int lsb = (u >> 16) & 1u;
    u += 0x7fffu + lsb;
    return (unsigned short)(u >> 16);
}

__device__ inline void gload16(const void* g, void* l) {
    __builtin_amdgcn_global_load_lds(
        (const __attribute__((address_space(1))) void*)g,
        (__attribute__((address_space(3))) void*)l, 16, 0, 0);
}

// ---------------- copy 8 N-length state arrays to output (pass-through) ----
__global__ void copy_kernel(const float* s0, const float* s1, const float* s2, const float* s3,
                            const float* s4, const float* s5, const float* s6, const float* s7,
                            float* dst) {
    const int n4 = N_ITEMS / 4;
    int k = blockIdx.y;
    const float* s;
    switch (k) {
        case 0: s = s0; break; case 1: s = s1; break;
        case 2: s = s2; break; case 3: s = s3; break;
        case 4: s = s4; break; case 5: s = s5; break;
        case 6: s = s6; break; default: s = s7; break;
    }
    float* d = dst + (size_t)k * N_ITEMS;
    for (int i = blockIdx.x * blockDim.x + threadIdx.x; i < n4; i += gridDim.x * blockDim.x) {
        float4 v = ((const float4*)s)[i];
        float* dd = d + (size_t)i * 4;   // dst is 4B-aligned only (offset 8193 floats)
        dd[0] = v.x; dd[1] = v.y; dd[2] = v.z; dd[3] = v.w;
    }
}

// ---------------- fp32 -> bf16 conversion of img / txt ---------------------
__global__ void convert_kernel(const float* __restrict__ img, const float* __restrict__ txt,
                               unsigned short* __restrict__ Xbf, unsigned short* __restrict__ Ybf) {
    const int per = (BDIM * DDIM) / 4;  // 786432 float4 units per array
    for (int u = blockIdx.x * blockDim.x + threadIdx.x; u < 2 * per; u += gridDim.x * blockDim.x) {
        const float4* src = (u < per) ? (const float4*)img : (const float4*)txt;
        unsigned short* dst = (u < per) ? Xbf : Ybf;
        int i = (u < per) ? u : u - per;
        float4 v = src[i];
        ushort4 o;
        o.x = f2bf(v.x); o.y = f2bf(v.y); o.z = f2bf(v.z); o.w = f2bf(v.w);
        ((ushort4*)dst)[i] = o;
    }
}

// ---------------- fp32 diagonal dot + tau gathers --------------------------
__global__ void diag_tau_kernel(const float* __restrict__ img, const float* __restrict__ txt,
                                const int* __restrict__ image_ids, const int* __restrict__ text_ids,
                                const float* __restrict__ tau_I, const float* __restrict__ tau_T,
                                float* __restrict__ diag, float* __restrict__ tau_row,
                                float* __restrict__ out /* d_out base */) {
    int w = (blockIdx.x * blockDim.x + threadIdx.x) >> 6;
    int lane = threadIdx.x & 63;
    if (w >= BDIM) return;
    const float* a = img + (size_t)w * DDIM;
    const float* b = txt + (size_t)w * DDIM;
    float s = 0.f;
    for (int d = lane; d < DDIM; d += 64) s += a[d] * b[d];
    #pragma unroll
    for (int d = 32; d >= 1; d >>= 1) s += __shfl_xor(s, d);
    if (lane == 0) diag[w] = s;
    if (lane == 1) {
        int id = image_ids[w];
        float t = tau_I[id];
        tau_row[w] = t;
        out[1 + w] = t;           // output 1: tau_image
    }
    if (lane == 2) {
        int id = text_ids[w];
        float t = tau_T[id];
        tau_row[BDIM + w] = t;
        out[1 + BDIM + w] = t;    // output 2: tau_text
    }
}

// ---------------- fused bf16 MFMA GEMM + per-chunk online softmax ----------
// m97 pattern: 128x128 tile, BK=32, global_load_lds width=16 into LINEAR LDS.
// grid: (32 colblocks, 32 rowblocks, 2 passes), 256 threads (4 waves, 2x2)
__global__ __launch_bounds__(256) void gemm_kernel(
        const unsigned short* __restrict__ Xbf, const unsigned short* __restrict__ Ybf,
        const float* __restrict__ diag, const float* __restrict__ tau_row,
        float* __restrict__ partials /* [2][4096][64][3] */) {
    __shared__ unsigned short As[128 * 32];   // linear: required by global_load_lds
    __shared__ unsigned short Bs[128 * 32];
    const int tid = threadIdx.x;
    const int lane = tid & 63;
    const int wave = tid >> 6;
    const int wr = wave >> 1, wc = wave & 1;
    const int cb = blockIdx.x, rb = blockIdx.y, p = blockIdx.z;
    const unsigned short* Xp = p ? Ybf : Xbf;
    const unsigned short* Yp = p ? Xbf : Ybf;

    f32x4 acc[4][4];
    #pragma unroll
    for (int m = 0; m < 4; m++)
        #pragma unroll
        for (int n = 0; n < 4; n++)
            #pragma unroll
            for (int q = 0; q < 4; q++) acc[m][n][q] = 0.f;

    const int g = lane >> 4, r16 = lane & 15;

    // staging geometry: wave w stages LDS bytes [w*2048, (w+1)*2048) of each
    // tile as 2 instrs of 1024B; lane l covers base + l*16.
    // LDS byte off -> row = off>>6 (64B per 32-ushort row), colbyte = off&63.
    const int srow0 = wave * 32 + (lane >> 2);      // j=0 chunk rows
    const int scb   = (lane & 3) * 16;              // col byte within row
    const char* gA0 = (const char*)Xp + ((size_t)(rb * 128 + srow0) * DDIM) * 2 + scb;
    const char* gA1 = gA0 + (size_t)16 * DDIM * 2;  // j=1: +16 rows
    const char* gB0 = (const char*)Yp + ((size_t)(cb * 128 + srow0) * DDIM) * 2 + scb;
    const char* gB1 = gB0 + (size_t)16 * DDIM * 2;
    char* lA0 = (char*)As + wave * 2048;
    char* lA1 = lA0 + 1024;
    char* lB0 = (char*)Bs + wave * 2048;
    char* lB1 = lB0 + 1024;

    for (int kk = 0; kk < 24; ++kk) {
        __syncthreads();
        const size_t ko = (size_t)kk * 64;          // 32 ushorts = 64 bytes
        gload16(gA0 + ko, lA0);
        gload16(gA1 + ko, lA1);
        gload16(gB0 + ko, lB0);
        gload16(gB1 + ko, lB1);
        __syncthreads();                            // compiler drains vmcnt before barrier
        bf16x8 af[4], bfr[4];
        #pragma unroll
        for (int m = 0; m < 4; m++) af[m]  = *(const bf16x8*)&As[(wr * 64 + m * 16 + r16) * 32 + g * 8];
        #pragma unroll
        for (int n = 0; n < 4; n++) bfr[n] = *(const bf16x8*)&Bs[(wc * 64 + n * 16 + r16) * 32 + g * 8];
        #pragma unroll
        for (int m = 0; m < 4; m++)
            #pragma unroll
            for (int n = 0; n < 4; n++)
                acc[m][n] = __builtin_amdgcn_mfma_f32_16x16x32_bf16(af[m], bfr[n], acc[m][n], 0, 0, 0);
    }

    // epilogue: per-row online (m, E=sum e, F=sum e*x) over this wave's 64 cols
    const float* taup = tau_row + p * BDIM;
    const int R0 = rb * 128 + wr * 64;
    const int C0 = cb * 128 + wc * 64;
    #pragma unroll
    for (int m = 0; m < 4; m++) {
        #pragma unroll
        for (int q = 0; q < 4; q++) {
            const int rowg = R0 + m * 16 + g * 4 + q;
            const float dgv = diag[rowg];
            const float itau = 1.0f / taup[rowg];
            float mloc = -3.0e38f, E = 0.f, F = 0.f;
            #pragma unroll
            for (int n = 0; n < 4; n++) {
                const int colg = C0 + n * 16 + r16;
                if (colg == rowg) continue;          // mask_neg: skip diagonal
                float x = (acc[m][n][q] - dgv) * itau;
                if (x > mloc) {
                    float sc = __expf(mloc - x);
                    E *= sc; F *= sc; mloc = x;
                }
                float e = __expf(x - mloc);
                E += e; F += e * x;
            }
            #pragma unroll
            for (int d = 1; d < 16; d <<= 1) {
                float mo = __shfl_xor(mloc, d);
                float Eo = __shfl_xor(E, d);
                float Fo = __shfl_xor(F, d);
                float mn = fmaxf(mloc, mo);
                float s1 = __expf(mloc - mn), s2 = __expf(mo - mn);
                E = E * s1 + Eo * s2;
                F = F * s1 + Fo * s2;
                mloc = mn;
            }
            if (r16 == 0) {
                const int chunk = cb * 2 + wc;       // 64-col chunk id, 0..63
                float* pp = partials + (((size_t)p * BDIM + rowg) * 64 + chunk) * 3;
                pp[0] = mloc; pp[1] = E; pp[2] = F;
            }
        }
    }
}

// ---------------- merge 64 chunk-partials per row + scalar tail math -------
__global__ void combine_kernel(const float* __restrict__ partials,
        const int* __restrict__ image_ids, const int* __restrict__ text_ids,
        const float* __restrict__ b_I, const float* __restrict__ b_T,
        const float* __restrict__ s_I, const float* __restrict__ s_T,
        const float* __restrict__ u_I, const float* __restrict__ u_T,
        const float* __restrict__ tau_row, const int* __restrict__ epoch_ptr,
        float* __restrict__ res /* [2][4096][5] = newb,s,u,tau,loss */) {
    int gw = (blockIdx.x * blockDim.x + threadIdx.x) >> 6;
    int lane = threadIdx.x & 63;
    if (gw >= 2 * BDIM) return;
    int p = gw >> 12, row = gw & (BDIM - 1);
    const float* pp = partials + (((size_t)p * BDIM + row) * 64 + lane) * 3;
    float m = pp[0], E = pp[1], F = pp[2];
    #pragma unroll
    for (int d = 1; d < 64; d <<= 1) {
        float mo = __shfl_xor(m, d), Eo = __shfl_xor(E, d), Fo = __shfl_xor(F, d);
        float mn = fmaxf(m, mo);
        float s1 = expf(m - mn), s2 = expf(mo - mn);
        E = E * s1 + Eo * s2;
        F = F * s1 + Fo * s2;
        m = mn;
    }
    if (lane == 0) {
        int id  = p ? text_ids[row] : image_ids[row];
        float ob = p ? b_T[id] : b_I[id];
        float so = p ? s_T[id] : s_I[id];
        float uo = p ? u_T[id] : u_I[id];
        float tv = tau_row[p * BDIM + row];
        float m0 = fmaxf(ob, 0.0f);        // reference max includes idt[i,i]=0 and old_b
        if (m0 > m) { float sc = expf(m - m0); E *= sc; F *= sc; m = m0; }
        float gsum = E;
        float sI = (*epoch_ptr == 0) ? gsum
                 : 0.2f * so * expf(ob - m) + 0.8f * gsum;
        float sc_ = fmaxf(sI, 1e-14f);
        float ratio = F / sc_;
        float lossv = tv * ratio;                                  // sum(w*diffs)
        float twi = logf(sc_ * (1.0f / 4095.0f)) + m + 8.0f - ratio;
        float uc = fminf(fmaxf(twi, -5.0f), 5.0f);
        float ub = 0.5f * uo + 0.5f * uc;
        float tb = fminf(fmaxf(tv - 0.03f * ub, 0.005f), 0.05f);
        float* r_ = res + ((size_t)p * BDIM + row) * 5;
        r_[0] = m; r_[1] = sI; r_[2] = ub; r_[3] = tb; r_[4] = lossv;
    }
}

// ---------------- scatter: last-occurrence-wins via LDS id scan ------------
__global__ __launch_bounds__(256) void scatter_kernel(const float* __restrict__ res,
        const int* __restrict__ image_ids, const int* __restrict__ text_ids,
        float* __restrict__ out) {
    __shared__ int sids[BDIM];
    const int p = blockIdx.x >> 4;                  // 16 blocks per side
    const int* ids = p ? text_ids : image_ids;
    for (int i = threadIdx.x; i < BDIM; i += 256) sids[i] = ids[i];
    __syncthreads();
    const int b = (blockIdx.x & 15) * 256 + threadIdx.x;
    const int myid = sids[b];
    for (int b2 = b + 1; b2 < BDIM; ++b2)
        if (sids[b2] == myid) return;               // a later duplicate wins
    const float* r_ = res + ((size_t)p * BDIM + b) * 5;
    const size_t base = 1 + 2 * BDIM;               // 8193
    out[base + (size_t)(2 + p) * N_ITEMS + myid] = r_[0];  // b_I / b_T
    out[base + (size_t)(0 + p) * N_ITEMS + myid] = r_[1];  // s_I / s_T
    out[base + (size_t)(4 + p) * N_ITEMS + myid] = r_[2];  // u_I / u_T
    out[base + (size_t)(6 + p) * N_ITEMS + myid] = r_[3];  // tau_I / tau_T
}

// ---------------- deterministic loss reduction -----------------------------
__global__ void loss_kernel(const float* __restrict__ res, float* __restrict__ out) {
    __shared__ float wsum[16];
    int t = threadIdx.x;
    float s = 0.f;
    for (int i = t; i < 2 * BDIM; i += 1024) s += res[(size_t)i * 5 + 4];
    #pragma unroll
    for (int d = 32; d >= 1; d >>= 1) s += __shfl_xor(s, d);
    if ((t & 63) == 0) wsum[t >> 6] = s;
    __syncthreads();
    if (t == 0) {
        float tot = 0.f;
        for (int i = 0; i < 16; i++) tot += wsum[i];
        out[0] = tot * (1.0f / (float)BDIM);  // mean(img)+mean(txt) = sum(all)/B
    }
}

extern "C" void kernel_launch(void* const* d_in, const int* in_sizes, int n_in,
                              void* d_out, int out_size, void* d_ws, size_t ws_size,
                              hipStream_t stream) {
    const float* img       = (const float*)d_in[0];
    const float* txt       = (const float*)d_in[1];
    const int*   image_ids = (const int*)d_in[2];
    const int*   text_ids  = (const int*)d_in[3];
    const int*   epoch     = (const int*)d_in[4];
    const float* s_I   = (const float*)d_in[6];
    const float* s_T   = (const float*)d_in[7];
    const float* b_I   = (const float*)d_in[8];
    const float* b_T   = (const float*)d_in[9];
    const float* u_I   = (const float*)d_in[10];
    const float* u_T   = (const float*)d_in[11];
    const float* tau_I = (const float*)d_in[12];
    const float* tau_T = (const float*)d_in[13];
    float* out = (float*)d_out;

    char* ws = (char*)d_ws;
    unsigned short* Xbf = (unsigned short*)ws;                    // 6,291,456 B
    unsigned short* Ybf = (unsigned short*)(ws + 6291456);        // 6,291,456 B
    float* diag     = (float*)(ws + 12582912);                    // 16 KB
    float* tau_row  = (float*)(ws + 12599296);                    // 32 KB
    float* partials = (float*)(ws + 12632064);                    // 6,291,456 B
    float* res      = (float*)(ws + 18923520);                    // 160 KB

    copy_kernel<<<dim3(512, 8), 256, 0, stream>>>(s_I, s_T, b_I, b_T, u_I, u_T, tau_I, tau_T,
                                                  out + 1 + 2 * BDIM);
    convert_kernel<<<1536, 256, 0, stream>>>(img, txt, Xbf, Ybf);
    diag_tau_kernel<<<1024, 256, 0, stream>>>(img, txt, image_ids, text_ids, tau_I, tau_T,
                                              diag, tau_row, out);
    gemm_kernel<<<dim3(32, 32, 2), 256, 0, stream>>>(Xbf, Ybf, diag, tau_row, partials);
    combine_kernel<<<2048, 256, 0, stream>>>(partials, image_ids, text_ids,
                                             b_I, b_T, s_I, s_T, u_I, u_T,
                                             tau_row, epoch, res);
    scatter_kernel<<<32, 256, 0, stream>>>(res, image_ids, text_ids, out);
    loss_kernel<<<1, 1024, 0, stream>>>(res, out);
}

// Round 3
// 157.441 us; speedup vs baseline: 3.5688x; 3.0662x over previous
//
#include <hip/hip_runtime.h>
#include <hip/hip_bf16.h>
#include <math.h>

#define N_ITEMS 2900000
#define BDIM 4096
#define DDIM 768

typedef float f32x4 __attribute__((ext_vector_type(4)));
typedef __bf16 bf16x8 __attribute__((ext_vector_type(8)));

__device__ inline unsigned short f2bf(float f) {
    unsigned int u = __float_as_uint(f);
    unsigned int lsb = (u >> 16) & 1u;
    u += 0x7fffu + lsb;
    return (unsigned short)(u >> 16);
}

__device__ inline void gload16(const void* g, void* l) {
    __builtin_amdgcn_global_load_lds(
        (const __attribute__((address_space(1))) void*)g,
        (__attribute__((address_space(3))) void*)l, 16, 0, 0);
}

// ---------------- copy 8 N-length state arrays to output (pass-through) ----
__global__ void copy_kernel(const float* s0, const float* s1, const float* s2, const float* s3,
                            const float* s4, const float* s5, const float* s6, const float* s7,
                            float* dst) {
    const int n4 = N_ITEMS / 4;
    int k = blockIdx.y;
    const float* s;
    switch (k) {
        case 0: s = s0; break; case 1: s = s1; break;
        case 2: s = s2; break; case 3: s = s3; break;
        case 4: s = s4; break; case 5: s = s5; break;
        case 6: s = s6; break; default: s = s7; break;
    }
    float* d = dst + (size_t)k * N_ITEMS;
    for (int i = blockIdx.x * blockDim.x + threadIdx.x; i < n4; i += gridDim.x * blockDim.x) {
        float4 v = ((const float4*)s)[i];
        float* dd = d + (size_t)i * 4;   // dst is 4B-aligned only (offset 8193 floats)
        dd[0] = v.x; dd[1] = v.y; dd[2] = v.z; dd[3] = v.w;
    }
}

// ---------------- fp32 -> bf16 conversion of img / txt ---------------------
__global__ void convert_kernel(const float* __restrict__ img, const float* __restrict__ txt,
                               unsigned short* __restrict__ Xbf, unsigned short* __restrict__ Ybf) {
    const int per = (BDIM * DDIM) / 4;  // 786432 float4 units per array
    for (int u = blockIdx.x * blockDim.x + threadIdx.x; u < 2 * per; u += gridDim.x * blockDim.x) {
        const float4* src = (u < per) ? (const float4*)img : (const float4*)txt;
        unsigned short* dst = (u < per) ? Xbf : Ybf;
        int i = (u < per) ? u : u - per;
        float4 v = src[i];
        ushort4 o;
        o.x = f2bf(v.x); o.y = f2bf(v.y); o.z = f2bf(v.z); o.w = f2bf(v.w);
        ((ushort4*)dst)[i] = o;
    }
}

// ---------------- fp32 diagonal dot + tau gathers --------------------------
__global__ void diag_tau_kernel(const float* __restrict__ img, const float* __restrict__ txt,
                                const int* __restrict__ image_ids, const int* __restrict__ text_ids,
                                const float* __restrict__ tau_I, const float* __restrict__ tau_T,
                                float* __restrict__ diag, float* __restrict__ tau_row,
                                float* __restrict__ out /* d_out base */) {
    int w = (blockIdx.x * blockDim.x + threadIdx.x) >> 6;
    int lane = threadIdx.x & 63;
    if (w >= BDIM) return;
    const float* a = img + (size_t)w * DDIM;
    const float* b = txt + (size_t)w * DDIM;
    float s = 0.f;
    for (int d = lane; d < DDIM; d += 64) s += a[d] * b[d];
    #pragma unroll
    for (int d = 32; d >= 1; d >>= 1) s += __shfl_xor(s, d);
    if (lane == 0) diag[w] = s;
    if (lane == 1) {
        int id = image_ids[w];
        float t = tau_I[id];
        tau_row[w] = t;
        out[1 + w] = t;           // output 1: tau_image
    }
    if (lane == 2) {
        int id = text_ids[w];
        float t = tau_T[id];
        tau_row[BDIM + w] = t;
        out[1 + BDIM + w] = t;    // output 2: tau_text
    }
}

// ---------------- fused bf16 MFMA GEMM + per-chunk online softmax ----------
// m97 pattern: 128x128 tile, BK=32, global_load_lds width=16 into LINEAR LDS.
// grid: (32 colblocks, 32 rowblocks, 2 passes), 256 threads (4 waves, 2x2)
__global__ __launch_bounds__(256) void gemm_kernel(
        const unsigned short* __restrict__ Xbf, const unsigned short* __restrict__ Ybf,
        const float* __restrict__ diag, const float* __restrict__ tau_row,
        float* __restrict__ partials /* [2][4096][64][3] */) {
    __shared__ unsigned short As[128 * 32];   // linear: required by global_load_lds
    __shared__ unsigned short Bs[128 * 32];
    const int tid = threadIdx.x;
    const int lane = tid & 63;
    const int wave = tid >> 6;
    const int wr = wave >> 1, wc = wave & 1;
    const int cb = blockIdx.x, rb = blockIdx.y, p = blockIdx.z;
    const unsigned short* Xp = p ? Ybf : Xbf;
    const unsigned short* Yp = p ? Xbf : Ybf;

    f32x4 acc[4][4];
    #pragma unroll
    for (int m = 0; m < 4; m++)
        #pragma unroll
        for (int n = 0; n < 4; n++)
            #pragma unroll
            for (int q = 0; q < 4; q++) acc[m][n][q] = 0.f;

    const int g = lane >> 4, r16 = lane & 15;

    // staging geometry: wave w stages LDS bytes [w*2048, (w+1)*2048) of each
    // tile as 2 instrs of 1024B; lane l covers base + l*16.
    const int srow0 = wave * 32 + (lane >> 2);      // j=0 chunk rows
    const int scb   = (lane & 3) * 16;              // col byte within row
    const char* gA0 = (const char*)Xp + ((size_t)(rb * 128 + srow0) * DDIM) * 2 + scb;
    const char* gA1 = gA0 + (size_t)16 * DDIM * 2;  // j=1: +16 rows
    const char* gB0 = (const char*)Yp + ((size_t)(cb * 128 + srow0) * DDIM) * 2 + scb;
    const char* gB1 = gB0 + (size_t)16 * DDIM * 2;
    char* lA0 = (char*)As + wave * 2048;
    char* lA1 = lA0 + 1024;
    char* lB0 = (char*)Bs + wave * 2048;
    char* lB1 = lB0 + 1024;

    for (int kk = 0; kk < 24; ++kk) {
        __syncthreads();
        const size_t ko = (size_t)kk * 64;          // 32 ushorts = 64 bytes
        gload16(gA0 + ko, lA0);
        gload16(gA1 + ko, lA1);
        gload16(gB0 + ko, lB0);
        gload16(gB1 + ko, lB1);
        __syncthreads();                            // compiler drains vmcnt before barrier
        bf16x8 af[4], bfr[4];
        #pragma unroll
        for (int m = 0; m < 4; m++) af[m]  = *(const bf16x8*)&As[(wr * 64 + m * 16 + r16) * 32 + g * 8];
        #pragma unroll
        for (int n = 0; n < 4; n++) bfr[n] = *(const bf16x8*)&Bs[(wc * 64 + n * 16 + r16) * 32 + g * 8];
        #pragma unroll
        for (int m = 0; m < 4; m++)
            #pragma unroll
            for (int n = 0; n < 4; n++)
                acc[m][n] = __builtin_amdgcn_mfma_f32_16x16x32_bf16(af[m], bfr[n], acc[m][n], 0, 0, 0);
    }

    // epilogue: per-row online (m, E=sum e, F=sum e*x) over this wave's 64 cols
    const float* taup = tau_row + p * BDIM;
    const int R0 = rb * 128 + wr * 64;
    const int C0 = cb * 128 + wc * 64;
    #pragma unroll
    for (int m = 0; m < 4; m++) {
        #pragma unroll
        for (int q = 0; q < 4; q++) {
            const int rowg = R0 + m * 16 + g * 4 + q;
            const float dgv = diag[rowg];
            const float itau = 1.0f / taup[rowg];
            float mloc = -3.0e38f, E = 0.f, F = 0.f;
            #pragma unroll
            for (int n = 0; n < 4; n++) {
                const int colg = C0 + n * 16 + r16;
                if (colg == rowg) continue;          // mask_neg: skip diagonal
                float x = (acc[m][n][q] - dgv) * itau;
                if (x > mloc) {
                    float sc = __expf(mloc - x);
                    E *= sc; F *= sc; mloc = x;
                }
                float e = __expf(x - mloc);
                E += e; F += e * x;
            }
            #pragma unroll
            for (int d = 1; d < 16; d <<= 1) {
                float mo = __shfl_xor(mloc, d);
                float Eo = __shfl_xor(E, d);
                float Fo = __shfl_xor(F, d);
                float mn = fmaxf(mloc, mo);
                float s1 = __expf(mloc - mn), s2 = __expf(mo - mn);
                E = E * s1 + Eo * s2;
                F = F * s1 + Fo * s2;
                mloc = mn;
            }
            if (r16 == 0) {
                const int chunk = cb * 2 + wc;       // 64-col chunk id, 0..63
                float* pp = partials + (((size_t)p * BDIM + rowg) * 64 + chunk) * 3;
                pp[0] = mloc; pp[1] = E; pp[2] = F;
            }
        }
    }
}

// ---------------- merge 64 chunk-partials per row + scalar tail math -------
__global__ void combine_kernel(const float* __restrict__ partials,
        const int* __restrict__ image_ids, const int* __restrict__ text_ids,
        const float* __restrict__ b_I, const float* __restrict__ b_T,
        const float* __restrict__ s_I, const float* __restrict__ s_T,
        const float* __restrict__ u_I, const float* __restrict__ u_T,
        const float* __restrict__ tau_row, const int* __restrict__ epoch_ptr,
        float* __restrict__ res /* [2][4096][5] = newb,s,u,tau,loss */) {
    int gw = (blockIdx.x * blockDim.x + threadIdx.x) >> 6;
    int lane = threadIdx.x & 63;
    if (gw >= 2 * BDIM) return;
    int p = gw >> 12, row = gw & (BDIM - 1);
    const float* pp = partials + (((size_t)p * BDIM + row) * 64 + lane) * 3;
    float m = pp[0], E = pp[1], F = pp[2];
    #pragma unroll
    for (int d = 1; d < 64; d <<= 1) {
        float mo = __shfl_xor(m, d), Eo = __shfl_xor(E, d), Fo = __shfl_xor(F, d);
        float mn = fmaxf(m, mo);
        float s1 = expf(m - mn), s2 = expf(mo - mn);
        E = E * s1 + Eo * s2;
        F = F * s1 + Fo * s2;
        m = mn;
    }
    if (lane == 0) {
        int id  = p ? text_ids[row] : image_ids[row];
        float ob = p ? b_T[id] : b_I[id];
        float so = p ? s_T[id] : s_I[id];
        float uo = p ? u_T[id] : u_I[id];
        float tv = tau_row[p * BDIM + row];
        float m0 = fmaxf(ob, 0.0f);        // reference max includes idt[i,i]=0 and old_b
        if (m0 > m) { float sc = expf(m - m0); E *= sc; F *= sc; m = m0; }
        float gsum = E;
        float sI = (*epoch_ptr == 0) ? gsum
                 : 0.2f * so * expf(ob - m) + 0.8f * gsum;
        float sc_ = fmaxf(sI, 1e-14f);
        float ratio = F / sc_;
        float lossv = tv * ratio;                                  // sum(w*diffs)
        float twi = logf(sc_ * (1.0f / 4095.0f)) + m + 8.0f - ratio;
        float uc = fminf(fmaxf(twi, -5.0f), 5.0f);
        float ub = 0.5f * uo + 0.5f * uc;
        float tb = fminf(fmaxf(tv - 0.03f * ub, 0.005f), 0.05f);
        float* r_ = res + ((size_t)p * BDIM + row) * 5;
        r_[0] = m; r_[1] = sI; r_[2] = ub; r_[3] = tb; r_[4] = lossv;
    }
}

// ---------------- scatter: last-occurrence-wins, one WAVE per row ----------
// The duplicate scan is wave-parallel: lane l probes sids[b+1+l+64k], then a
// single __any() decides. 64 independent pipelined LDS reads per wave instead
// of a 4096-deep serial latency chain.
__global__ __launch_bounds__(256) void scatter_kernel(const float* __restrict__ res,
        const int* __restrict__ image_ids, const int* __restrict__ text_ids,
        float* __restrict__ out) {
    __shared__ int sids[BDIM];
    const int p = blockIdx.x >> 10;                 // 1024 blocks per side
    const int* ids = p ? text_ids : image_ids;
    for (int i = threadIdx.x; i < BDIM / 4; i += 256)
        ((int4*)sids)[i] = ((const int4*)ids)[i];
    __syncthreads();
    const int wave = threadIdx.x >> 6;              // 4 waves = 4 rows per block
    const int lane = threadIdx.x & 63;
    const int b = (blockIdx.x & 1023) * 4 + wave;
    const int myid = sids[b];
    bool dup = false;
    for (int c = b + 1 + lane; c < BDIM; c += 64)
        dup |= (sids[c] == myid);
    if (__any(dup)) return;                         // a later duplicate wins
    if (lane < 4) {
        const float v = res[((size_t)p * BDIM + b) * 5 + lane];  // m,sI,ub,tb
        const int arr = (lane == 0) ? (2 + p) : (lane == 1) ? (0 + p)
                      : (lane == 2) ? (4 + p) : (6 + p);
        out[8193 + (size_t)arr * N_ITEMS + myid] = v;
    }
}

// ---------------- deterministic loss reduction -----------------------------
__global__ void loss_kernel(const float* __restrict__ res, float* __restrict__ out) {
    __shared__ float wsum[16];
    int t = threadIdx.x;
    float s = 0.f;
    for (int i = t; i < 2 * BDIM; i += 1024) s += res[(size_t)i * 5 + 4];
    #pragma unroll
    for (int d = 32; d >= 1; d >>= 1) s += __shfl_xor(s, d);
    if ((t & 63) == 0) wsum[t >> 6] = s;
    __syncthreads();
    if (t == 0) {
        float tot = 0.f;
        for (int i = 0; i < 16; i++) tot += wsum[i];
        out[0] = tot * (1.0f / (float)BDIM);  // mean(img)+mean(txt) = sum(all)/B
    }
}

extern "C" void kernel_launch(void* const* d_in, const int* in_sizes, int n_in,
                              void* d_out, int out_size, void* d_ws, size_t ws_size,
                              hipStream_t stream) {
    const float* img       = (const float*)d_in[0];
    const float* txt       = (const float*)d_in[1];
    const int*   image_ids = (const int*)d_in[2];
    const int*   text_ids  = (const int*)d_in[3];
    const int*   epoch     = (const int*)d_in[4];
    const float* s_I   = (const float*)d_in[6];
    const float* s_T   = (const float*)d_in[7];
    const float* b_I   = (const float*)d_in[8];
    const float* b_T   = (const float*)d_in[9];
    const float* u_I   = (const float*)d_in[10];
    const float* u_T   = (const float*)d_in[11];
    const float* tau_I = (const float*)d_in[12];
    const float* tau_T = (const float*)d_in[13];
    float* out = (float*)d_out;

    char* ws = (char*)d_ws;
    unsigned short* Xbf = (unsigned short*)ws;                    // 6,291,456 B
    unsigned short* Ybf = (unsigned short*)(ws + 6291456);        // 6,291,456 B
    float* diag     = (float*)(ws + 12582912);                    // 16 KB
    float* tau_row  = (float*)(ws + 12599296);                    // 32 KB
    float* partials = (float*)(ws + 12632064);                    // 6,291,456 B
    float* res      = (float*)(ws + 18923520);                    // 160 KB

    copy_kernel<<<dim3(512, 8), 256, 0, stream>>>(s_I, s_T, b_I, b_T, u_I, u_T, tau_I, tau_T,
                                                  out + 1 + 2 * BDIM);
    convert_kernel<<<1536, 256, 0, stream>>>(img, txt, Xbf, Ybf);
    diag_tau_kernel<<<1024, 256, 0, stream>>>(img, txt, image_ids, text_ids, tau_I, tau_T,
                                              diag, tau_row, out);
    gemm_kernel<<<dim3(32, 32, 2), 256, 0, stream>>>(Xbf, Ybf, diag, tau_row, partials);
    combine_kernel<<<2048, 256, 0, stream>>>(partials, image_ids, text_ids,
                                             b_I, b_T, s_I, s_T, u_I, u_T,
                                             tau_row, epoch, res);
    scatter_kernel<<<2048, 256, 0, stream>>>(res, image_ids, text_ids, out);
    loss_kernel<<<1, 1024, 0, stream>>>(res, out);
}

// Round 4
// 124.513 us; speedup vs baseline: 4.5126x; 1.2645x over previous
//
#include <hip/hip_runtime.h>
#include <hip/hip_bf16.h>
#include <math.h>

#define N_ITEMS 2900000
#define BDIM 4096
#define DDIM 768

typedef float f32x4 __attribute__((ext_vector_type(4)));
typedef __bf16 bf16x8 __attribute__((ext_vector_type(8)));

__device__ inline unsigned short f2bf(float f) {
    unsigned int u = __float_as_uint(f);
    unsigned int lsb = (u >> 16) & 1u;
    u += 0x7fffu + lsb;
    return (unsigned short)(u >> 16);
}

__device__ inline void gload16(const void* g, void* l) {
    __builtin_amdgcn_global_load_lds(
        (const __attribute__((address_space(1))) void*)g,
        (__attribute__((address_space(3))) void*)l, 16, 0, 0);
}

// ---------------- copy 8 N-length state arrays to output (pass-through) ----
__global__ void copy_kernel(const float* s0, const float* s1, const float* s2, const float* s3,
                            const float* s4, const float* s5, const float* s6, const float* s7,
                            float* dst) {
    const int n4 = N_ITEMS / 4;
    int k = blockIdx.y;
    const float* s;
    switch (k) {
        case 0: s = s0; break; case 1: s = s1; break;
        case 2: s = s2; break; case 3: s = s3; break;
        case 4: s = s4; break; case 5: s = s5; break;
        case 6: s = s6; break; default: s = s7; break;
    }
    float* d = dst + (size_t)k * N_ITEMS;
    for (int i = blockIdx.x * blockDim.x + threadIdx.x; i < n4; i += gridDim.x * blockDim.x) {
        float4 v = ((const float4*)s)[i];
        float* dd = d + (size_t)i * 4;   // dst is 4B-aligned only (offset 8193 floats)
        dd[0] = v.x; dd[1] = v.y; dd[2] = v.z; dd[3] = v.w;
    }
}

// ---------------- fp32 -> bf16 conversion of img / txt ---------------------
__global__ void convert_kernel(const float* __restrict__ img, const float* __restrict__ txt,
                               unsigned short* __restrict__ Xbf, unsigned short* __restrict__ Ybf) {
    const int per = (BDIM * DDIM) / 4;  // 786432 float4 units per array
    for (int u = blockIdx.x * blockDim.x + threadIdx.x; u < 2 * per; u += gridDim.x * blockDim.x) {
        const float4* src = (u < per) ? (const float4*)img : (const float4*)txt;
        unsigned short* dst = (u < per) ? Xbf : Ybf;
        int i = (u < per) ? u : u - per;
        float4 v = src[i];
        ushort4 o;
        o.x = f2bf(v.x); o.y = f2bf(v.y); o.z = f2bf(v.z); o.w = f2bf(v.w);
        ((ushort4*)dst)[i] = o;
    }
}

// ---------------- fp32 diagonal dot + tau gathers --------------------------
__global__ void diag_tau_kernel(const float* __restrict__ img, const float* __restrict__ txt,
                                const int* __restrict__ image_ids, const int* __restrict__ text_ids,
                                const float* __restrict__ tau_I, const float* __restrict__ tau_T,
                                float* __restrict__ diag, float* __restrict__ tau_row,
                                float* __restrict__ out /* d_out base */) {
    int w = (blockIdx.x * blockDim.x + threadIdx.x) >> 6;
    int lane = threadIdx.x & 63;
    if (w >= BDIM) return;
    const float* a = img + (size_t)w * DDIM;
    const float* b = txt + (size_t)w * DDIM;
    float s = 0.f;
    for (int d = lane; d < DDIM; d += 64) s += a[d] * b[d];
    #pragma unroll
    for (int d = 32; d >= 1; d >>= 1) s += __shfl_xor(s, d);
    if (lane == 0) diag[w] = s;
    if (lane == 1) {
        int id = image_ids[w];
        float t = tau_I[id];
        tau_row[w] = t;
        out[1 + w] = t;           // output 1: tau_image
    }
    if (lane == 2) {
        int id = text_ids[w];
        float t = tau_T[id];
        tau_row[BDIM + w] = t;
        out[1 + BDIM + w] = t;    // output 2: tau_text
    }
}

// ---------------- fused bf16 MFMA GEMM, dual-sided epilogue ----------------
// Computes sim ONCE; extracts row-side (image) stats AND col-side (text)
// stats from the same accumulator tile. Two-pass (max, then exp-sum) per side.
// grid: (32 colblocks, 32 rowblocks), 256 threads (4 waves, 2x2)
__global__ __launch_bounds__(256) void gemm_kernel(
        const unsigned short* __restrict__ Xbf, const unsigned short* __restrict__ Ybf,
        const float* __restrict__ diag, const float* __restrict__ tau_row,
        float* __restrict__ partials /* [2][4096][64][3] */) {
    __shared__ unsigned short As[128 * 32];   // linear: required by global_load_lds
    __shared__ unsigned short Bs[128 * 32];
    const int tid = threadIdx.x;
    const int lane = tid & 63;
    const int wave = tid >> 6;
    const int wr = wave >> 1, wc = wave & 1;
    const int cb = blockIdx.x, rb = blockIdx.y;

    f32x4 acc[4][4];
    #pragma unroll
    for (int m = 0; m < 4; m++)
        #pragma unroll
        for (int n = 0; n < 4; n++)
            #pragma unroll
            for (int q = 0; q < 4; q++) acc[m][n][q] = 0.f;

    const int g = lane >> 4, r16 = lane & 15;

    const int srow0 = wave * 32 + (lane >> 2);      // staging rows (j=0)
    const int scb   = (lane & 3) * 16;              // col byte within row
    const char* gA0 = (const char*)Xbf + ((size_t)(rb * 128 + srow0) * DDIM) * 2 + scb;
    const char* gA1 = gA0 + (size_t)16 * DDIM * 2;  // j=1: +16 rows
    const char* gB0 = (const char*)Ybf + ((size_t)(cb * 128 + srow0) * DDIM) * 2 + scb;
    const char* gB1 = gB0 + (size_t)16 * DDIM * 2;
    char* lA0 = (char*)As + wave * 2048;
    char* lA1 = lA0 + 1024;
    char* lB0 = (char*)Bs + wave * 2048;
    char* lB1 = lB0 + 1024;

    for (int kk = 0; kk < 24; ++kk) {
        __syncthreads();
        const size_t ko = (size_t)kk * 64;          // 32 ushorts = 64 bytes
        gload16(gA0 + ko, lA0);
        gload16(gA1 + ko, lA1);
        gload16(gB0 + ko, lB0);
        gload16(gB1 + ko, lB1);
        __syncthreads();
        bf16x8 af[4], bfr[4];
        #pragma unroll
        for (int m = 0; m < 4; m++) af[m]  = *(const bf16x8*)&As[(wr * 64 + m * 16 + r16) * 32 + g * 8];
        #pragma unroll
        for (int n = 0; n < 4; n++) bfr[n] = *(const bf16x8*)&Bs[(wc * 64 + n * 16 + r16) * 32 + g * 8];
        #pragma unroll
        for (int m = 0; m < 4; m++)
            #pragma unroll
            for (int n = 0; n < 4; n++)
                acc[m][n] = __builtin_amdgcn_mfma_f32_16x16x32_bf16(af[m], bfr[n], acc[m][n], 0, 0, 0);
    }

    const int R0 = rb * 128 + wr * 64;
    const int C0 = cb * 128 + wc * 64;

    // ---- row side (image): per (m,q) one row; 16 r16-lanes hold its 64 cols
    #pragma unroll
    for (int m = 0; m < 4; m++) {
        #pragma unroll
        for (int q = 0; q < 4; q++) {
            const int rowg = R0 + m * 16 + g * 4 + q;
            const float dgv = diag[rowg];
            const float itau = 1.0f / tau_row[rowg];
            float x4[4];
            float mloc = -3.0e38f;
            #pragma unroll
            for (int n = 0; n < 4; n++) {
                const int colg = C0 + n * 16 + r16;
                const float x = (acc[m][n][q] - dgv) * itau;
                x4[n] = x;
                mloc = (colg != rowg) ? fmaxf(mloc, x) : mloc;
            }
            #pragma unroll
            for (int d = 1; d < 16; d <<= 1) mloc = fmaxf(mloc, __shfl_xor(mloc, d));
            float E = 0.f, F = 0.f;
            #pragma unroll
            for (int n = 0; n < 4; n++) {
                const int colg = C0 + n * 16 + r16;
                const float e = (colg != rowg) ? __expf(x4[n] - mloc) : 0.f;
                E += e; F += e * x4[n];
            }
            #pragma unroll
            for (int d = 1; d < 16; d <<= 1) {
                E += __shfl_xor(E, d);
                F += __shfl_xor(F, d);
            }
            if (r16 == 0) {
                const int chunk = cb * 2 + wc;       // 64-col chunk id
                float* pp = partials + (((size_t)rowg) * 64 + chunk) * 3;
                pp[0] = mloc; pp[1] = E; pp[2] = F;
            }
        }
    }

    // ---- col side (text): per n one column per lane; g-lanes (str 16,32)
    //      hold its 64 rows
    #pragma unroll
    for (int n = 0; n < 4; n++) {
        const int colg = C0 + n * 16 + r16;
        const float dgc = diag[colg];
        const float itc = 1.0f / tau_row[BDIM + colg];
        float mloc = -3.0e38f;
        #pragma unroll
        for (int m = 0; m < 4; m++)
            #pragma unroll
            for (int q = 0; q < 4; q++) {
                const int rowg = R0 + m * 16 + g * 4 + q;
                const float x = (acc[m][n][q] - dgc) * itc;
                mloc = (rowg != colg) ? fmaxf(mloc, x) : mloc;
            }
        mloc = fmaxf(mloc, __shfl_xor(mloc, 16));
        mloc = fmaxf(mloc, __shfl_xor(mloc, 32));
        float E = 0.f, F = 0.f;
        #pragma unroll
        for (int m = 0; m < 4; m++)
            #pragma unroll
            for (int q = 0; q < 4; q++) {
                const int rowg = R0 + m * 16 + g * 4 + q;
                const float x = (acc[m][n][q] - dgc) * itc;
                const float e = (rowg != colg) ? __expf(x - mloc) : 0.f;
                E += e; F += e * x;
            }
        E += __shfl_xor(E, 16); F += __shfl_xor(F, 16);
        E += __shfl_xor(E, 32); F += __shfl_xor(F, 32);
        if (g == 0) {
            const int rchunk = rb * 2 + wr;          // 64-row chunk id
            float* pp = partials + (((size_t)BDIM + colg) * 64 + rchunk) * 3;
            pp[0] = mloc; pp[1] = E; pp[2] = F;
        }
    }
}

// ---------------- merge 64 chunk-partials per row + scalar tail math -------
__global__ void combine_kernel(const float* __restrict__ partials,
        const int* __restrict__ image_ids, const int* __restrict__ text_ids,
        const float* __restrict__ b_I, const float* __restrict__ b_T,
        const float* __restrict__ s_I, const float* __restrict__ s_T,
        const float* __restrict__ u_I, const float* __restrict__ u_T,
        const float* __restrict__ tau_row, const int* __restrict__ epoch_ptr,
        float* __restrict__ res /* [2][4096][5] = newb,s,u,tau,loss */) {
    int gw = (blockIdx.x * blockDim.x + threadIdx.x) >> 6;
    int lane = threadIdx.x & 63;
    if (gw >= 2 * BDIM) return;
    int p = gw >> 12, row = gw & (BDIM - 1);
    const float* pp = partials + (((size_t)p * BDIM + row) * 64 + lane) * 3;
    float m = pp[0], E = pp[1], F = pp[2];
    #pragma unroll
    for (int d = 1; d < 64; d <<= 1) {
        float mo = __shfl_xor(m, d), Eo = __shfl_xor(E, d), Fo = __shfl_xor(F, d);
        float mn = fmaxf(m, mo);
        float s1 = expf(m - mn), s2 = expf(mo - mn);
        E = E * s1 + Eo * s2;
        F = F * s1 + Fo * s2;
        m = mn;
    }
    if (lane == 0) {
        int id  = p ? text_ids[row] : image_ids[row];
        float ob = p ? b_T[id] : b_I[id];
        float so = p ? s_T[id] : s_I[id];
        float uo = p ? u_T[id] : u_I[id];
        float tv = tau_row[p * BDIM + row];
        float m0 = fmaxf(ob, 0.0f);        // reference max includes idt[i,i]=0 and old_b
        if (m0 > m) { float sc = expf(m - m0); E *= sc; F *= sc; m = m0; }
        float gsum = E;
        float sI = (*epoch_ptr == 0) ? gsum
                 : 0.2f * so * expf(ob - m) + 0.8f * gsum;
        float sc_ = fmaxf(sI, 1e-14f);
        float ratio = F / sc_;
        float lossv = tv * ratio;                                  // sum(w*diffs)
        float twi = logf(sc_ * (1.0f / 4095.0f)) + m + 8.0f - ratio;
        float uc = fminf(fmaxf(twi, -5.0f), 5.0f);
        float ub = 0.5f * uo + 0.5f * uc;
        float tb = fminf(fmaxf(tv - 0.03f * ub, 0.005f), 0.05f);
        float* r_ = res + ((size_t)p * BDIM + row) * 5;
        r_[0] = m; r_[1] = sI; r_[2] = ub; r_[3] = tb; r_[4] = lossv;
    }
}

// ---------------- scatter: last-occurrence-wins, one WAVE per row ----------
__global__ __launch_bounds__(256) void scatter_kernel(const float* __restrict__ res,
        const int* __restrict__ image_ids, const int* __restrict__ text_ids,
        float* __restrict__ out) {
    __shared__ int sids[BDIM];
    const int p = blockIdx.x >> 10;                 // 1024 blocks per side
    const int* ids = p ? text_ids : image_ids;
    for (int i = threadIdx.x; i < BDIM / 4; i += 256)
        ((int4*)sids)[i] = ((const int4*)ids)[i];
    __syncthreads();
    const int wave = threadIdx.x >> 6;              // 4 waves = 4 rows per block
    const int lane = threadIdx.x & 63;
    const int b = (blockIdx.x & 1023) * 4 + wave;
    const int myid = sids[b];
    bool dup = false;
    for (int c = b + 1 + lane; c < BDIM; c += 64)
        dup |= (sids[c] == myid);
    if (__any(dup)) return;                         // a later duplicate wins
    if (lane < 4) {
        const float v = res[((size_t)p * BDIM + b) * 5 + lane];  // m,sI,ub,tb
        const int arr = (lane == 0) ? (2 + p) : (lane == 1) ? (0 + p)
                      : (lane == 2) ? (4 + p) : (6 + p);
        out[8193 + (size_t)arr * N_ITEMS + myid] = v;
    }
}

// ---------------- deterministic loss reduction -----------------------------
__global__ void loss_kernel(const float* __restrict__ res, float* __restrict__ out) {
    __shared__ float wsum[16];
    int t = threadIdx.x;
    float s = 0.f;
    for (int i = t; i < 2 * BDIM; i += 1024) s += res[(size_t)i * 5 + 4];
    #pragma unroll
    for (int d = 32; d >= 1; d >>= 1) s += __shfl_xor(s, d);
    if ((t & 63) == 0) wsum[t >> 6] = s;
    __syncthreads();
    if (t == 0) {
        float tot = 0.f;
        for (int i = 0; i < 16; i++) tot += wsum[i];
        out[0] = tot * (1.0f / (float)BDIM);  // mean(img)+mean(txt) = sum(all)/B
    }
}

extern "C" void kernel_launch(void* const* d_in, const int* in_sizes, int n_in,
                              void* d_out, int out_size, void* d_ws, size_t ws_size,
                              hipStream_t stream) {
    const float* img       = (const float*)d_in[0];
    const float* txt       = (const float*)d_in[1];
    const int*   image_ids = (const int*)d_in[2];
    const int*   text_ids  = (const int*)d_in[3];
    const int*   epoch     = (const int*)d_in[4];
    const float* s_I   = (const float*)d_in[6];
    const float* s_T   = (const float*)d_in[7];
    const float* b_I   = (const float*)d_in[8];
    const float* b_T   = (const float*)d_in[9];
    const float* u_I   = (const float*)d_in[10];
    const float* u_T   = (const float*)d_in[11];
    const float* tau_I = (const float*)d_in[12];
    const float* tau_T = (const float*)d_in[13];
    float* out = (float*)d_out;

    char* ws = (char*)d_ws;
    unsigned short* Xbf = (unsigned short*)ws;                    // 6,291,456 B
    unsigned short* Ybf = (unsigned short*)(ws + 6291456);        // 6,291,456 B
    float* diag     = (float*)(ws + 12582912);                    // 16 KB
    float* tau_row  = (float*)(ws + 12599296);                    // 32 KB
    float* partials = (float*)(ws + 12632064);                    // 6,291,456 B
    float* res      = (float*)(ws + 18923520);                    // 160 KB

    copy_kernel<<<dim3(512, 8), 256, 0, stream>>>(s_I, s_T, b_I, b_T, u_I, u_T, tau_I, tau_T,
                                                  out + 1 + 2 * BDIM);
    convert_kernel<<<1536, 256, 0, stream>>>(img, txt, Xbf, Ybf);
    diag_tau_kernel<<<1024, 256, 0, stream>>>(img, txt, image_ids, text_ids, tau_I, tau_T,
                                              diag, tau_row, out);
    gemm_kernel<<<dim3(32, 32), 256, 0, stream>>>(Xbf, Ybf, diag, tau_row, partials);
    combine_kernel<<<2048, 256, 0, stream>>>(partials, image_ids, text_ids,
                                             b_I, b_T, s_I, s_T, u_I, u_T,
                                             tau_row, epoch, res);
    scatter_kernel<<<2048, 256, 0, stream>>>(res, image_ids, text_ids, out);
    loss_kernel<<<1, 1024, 0, stream>>>(res, out);
}